// Round 4
// baseline (637.915 us; speedup 1.0000x reference)
//
#include <hip/hip_runtime.h>

typedef __attribute__((ext_vector_type(8))) short short8;
typedef __attribute__((ext_vector_type(4))) float f32x4;

#define DEV static __device__ __forceinline__

constexpr int NN = 50000;       // nodes
constexpr int NE = 800000;      // edges
constexpr int NT_N = NN / 16;   // 3125 node tiles of 16 rows
constexpr int NT_E = NE / 16;   // 50000 edge tiles of 16 rows
constexpr int NB_SCAN = (NN + 255) / 256;  // 196
constexpr float EPS_BN = 1e-5f;
constexpr float EPS_NORM = 1e-12f;

// f32 -> bf16 (round-to-nearest-even)
DEV unsigned short f2b(float f) {
  unsigned u = __float_as_uint(f);
  return (unsigned short)((u + 0x7FFFu + ((u >> 16) & 1u)) >> 16);
}

// A-fragment for mfma_f32_16x16x32_bf16 from a row-major [*][64] f32 matrix.
// lane holds row (chosen per-lane), k = kbase + j (j=0..7)
DEV short8 load_a_frag(const float* __restrict__ base, int row, int kbase) {
  const f32x4* p = reinterpret_cast<const f32x4*>(base + row * 64 + kbase);
  f32x4 v0 = p[0], v1 = p[1];
  short8 a;
  a[0] = f2b(v0[0]); a[1] = f2b(v0[1]); a[2] = f2b(v0[2]); a[3] = f2b(v0[3]);
  a[4] = f2b(v1[0]); a[5] = f2b(v1[1]); a[6] = f2b(v1[2]); a[7] = f2b(v1[3]);
  return a;
}

// B-fragment: W is [K][64] row-major f32.
DEV short8 load_w_frag(const float* __restrict__ W, int kbase, int c0, int lane) {
  int kr = kbase + ((lane >> 4) << 3);
  int cc = c0 + (lane & 15);
  short8 b;
#pragma unroll
  for (int j = 0; j < 8; ++j) b[j] = f2b(W[(kr + j) * 64 + cc]);
  return b;
}

DEV f32x4 mfma16(short8 a, short8 b, f32x4 c) {
  return __builtin_amdgcn_mfma_f32_16x16x32_bf16(a, b, c, 0, 0, 0);
}

// ---------------- init: zero deg + stats ------------------------------------
__global__ void k_init(int* __restrict__ deg, float* __restrict__ stats) {
  int i = blockIdx.x * 256 + threadIdx.x;
  if (i < NN) deg[i] = 0;
  if (i < 512) stats[i] = 0.0f;
}

// ---------------- CSR build -------------------------------------------------
__global__ void k_deg(const int* __restrict__ dst, int* __restrict__ deg) {
  int i = blockIdx.x * 256 + threadIdx.x;
  if (i < NE) atomicAdd(&deg[dst[i]], 1);
}

__global__ void k_scan_local(const int* __restrict__ deg, int* __restrict__ off,
                             int* __restrict__ bsum) {
  __shared__ int sh[256];
  int t = threadIdx.x;
  int i = blockIdx.x * 256 + t;
  int v = (i < NN) ? deg[i] : 0;
  sh[t] = v;
  __syncthreads();
  for (int s = 1; s < 256; s <<= 1) {
    int u = (t >= s) ? sh[t - s] : 0;
    __syncthreads();
    sh[t] += u;
    __syncthreads();
  }
  if (i < NN) off[i] = sh[t] - v;
  if (t == 255) bsum[blockIdx.x] = sh[255];
}

__global__ void k_scan_base(const int* __restrict__ bsum, int* __restrict__ bbase) {
  __shared__ int sh[256];
  int t = threadIdx.x;
  int v = (t < NB_SCAN) ? bsum[t] : 0;
  sh[t] = v;
  __syncthreads();
  for (int s = 1; s < 256; s <<= 1) {
    int u = (t >= s) ? sh[t - s] : 0;
    __syncthreads();
    sh[t] += u;
    __syncthreads();
  }
  if (t < NB_SCAN) bbase[t] = sh[t] - v;
}

__global__ void k_scan_fix(const int* __restrict__ bbase, int* __restrict__ off,
                           int* __restrict__ cursor) {
  int i = blockIdx.x * 256 + threadIdx.x;
  if (i < NN) {
    int o = off[i] + bbase[blockIdx.x];
    off[i] = o;
    cursor[i] = o;
  }
}

__global__ void k_scatter(const int* __restrict__ dst, int* __restrict__ cursor,
                          int* __restrict__ perm) {
  int i = blockIdx.x * 256 + threadIdx.x;
  if (i < NE) {
    int p = atomicAdd(&cursor[dst[i]], 1);
    perm[p] = i;
  }
}

// ---------------- K1: Ah_p/Bh_p = (h@A_W+A_b, h@B_W+B_b), permuted layout ----
// Permuted layout: value for column c = t*16+r stored at [node*64 + r*4 + t],
// so a gather of the 4 t-values for fixed r is one f32x4 load.
__global__ void __launch_bounds__(256) k_node_lin(
    const float* __restrict__ h, const float* __restrict__ AW,
    const float* __restrict__ Ab, const float* __restrict__ BW,
    const float* __restrict__ Bb, float* __restrict__ Ah_p,
    float* __restrict__ Bh_p) {
  int lane = threadIdx.x & 63, warp = threadIdx.x >> 6;
  int tile = blockIdx.x * 4 + warp;
  if (tile >= NT_N) return;
  int r = lane & 15;

  short8 wa[4][2], wb[4][2];
  float ab[4], bb[4];
#pragma unroll
  for (int t = 0; t < 4; ++t) {
#pragma unroll
    for (int kk = 0; kk < 2; ++kk) {
      wa[t][kk] = load_w_frag(AW, kk * 32, t * 16, lane);
      wb[t][kk] = load_w_frag(BW, kk * 32, t * 16, lane);
    }
    ab[t] = Ab[t * 16 + r];
    bb[t] = Bb[t * 16 + r];
  }

  int row0 = tile * 16;
  int ar = row0 + r, kb = (lane >> 4) * 8;
  short8 a0 = load_a_frag(h, ar, kb);
  short8 a1 = load_a_frag(h, ar, 32 + kb);

  f32x4 zero = {0.f, 0.f, 0.f, 0.f};
  f32x4 accA[4], accB[4];
#pragma unroll
  for (int t = 0; t < 4; ++t) {
    accA[t] = mfma16(a0, wa[t][0], zero);
    accA[t] = mfma16(a1, wa[t][1], accA[t]);
    accB[t] = mfma16(a0, wb[t][0], zero);
    accB[t] = mfma16(a1, wb[t][1], accB[t]);
  }
#pragma unroll
  for (int q = 0; q < 4; ++q) {
    int row = row0 + (lane >> 4) * 4 + q;
    f32x4 va = {accA[0][q] + ab[0], accA[1][q] + ab[1], accA[2][q] + ab[2],
                accA[3][q] + ab[3]};
    f32x4 vb = {accB[0][q] + bb[0], accB[1][q] + bb[1], accB[2][q] + bb[2],
                accB[3][q] + bb[3]};
    *reinterpret_cast<f32x4*>(Ah_p + row * 64 + r * 4) = va;
    *reinterpret_cast<f32x4*>(Bh_p + row * 64 + r * 4) = vb;
  }
}

// ---------------- K2: dst-grouped edge pass (NO atomics) ---------------------
// One wave per node. For the node's incoming edges (via CSR perm):
//   e_ij = e[eid]@C_W + C_b + Bh[src] + Bh[node]
//   stats += relu(e_ij) (masked); m = max(m, relu(sigmoid(e_ij)*Ah[src]))
// Register max across lanes -> plain store of c[node]. No staging.
__global__ void __launch_bounds__(256) k_edge_grouped(
    const float* __restrict__ e, const int* __restrict__ src,
    const int* __restrict__ deg, const int* __restrict__ off,
    const int* __restrict__ perm, const float* __restrict__ CW,
    const float* __restrict__ Cb, const float* __restrict__ Ah_p,
    const float* __restrict__ Bh_p, float* __restrict__ cbuf,
    float* __restrict__ gsum, float* __restrict__ gsq) {
  __shared__ float ssum[64], ssq[64];
  int lane = threadIdx.x & 63, warp = threadIdx.x >> 6;
  int r = lane & 15, hi = lane >> 4;
  int node = blockIdx.x * 4 + warp;

  short8 cw[4][2];
  float cb[4];
#pragma unroll
  for (int t = 0; t < 4; ++t) {
#pragma unroll
    for (int kk = 0; kk < 2; ++kk) cw[t][kk] = load_w_frag(CW, kk * 32, t * 16, lane);
    cb[t] = Cb[t * 16 + r];
  }

  float es[4] = {0.f, 0.f, 0.f, 0.f}, eq[4] = {0.f, 0.f, 0.f, 0.f};
  float mreg[4] = {0.f, 0.f, 0.f, 0.f};
  f32x4 zero = {0.f, 0.f, 0.f, 0.f};

  if (node < NN) {
    int cnt = deg[node], base = off[node];
    if (cnt > 0) {
      // Bh[dst] == Bh[node]: one load for the whole wave
      f32x4 bd = *reinterpret_cast<const f32x4*>(Bh_p + node * 64 + r * 4);

      for (int c0 = 0; c0 < cnt; c0 += 16) {
        // lane's A-row: edge index min(c0+r, cnt-1)  (pad = dup of last edge)
        int i_r = c0 + r;
        int eid = perm[base + ((i_r < cnt) ? i_r : (cnt - 1))];
        int kb = hi * 8;
        short8 a0 = load_a_frag(e, eid, kb);
        short8 a1 = load_a_frag(e, eid, 32 + kb);

        f32x4 acc[4];
#pragma unroll
        for (int t = 0; t < 4; ++t) {
          acc[t] = mfma16(a0, cw[t][0], zero);
          acc[t] = mfma16(a1, cw[t][1], acc[t]);
        }

#pragma unroll
        for (int q = 0; q < 4; ++q) {
          int rowidx = hi * 4 + q;            // tile row this lane's acc holds
          // eid for tile row `rowidx` lives in lane `rowidx` (its r == rowidx)
          int er = __shfl(eid, rowidx);
          bool valid = (c0 + rowidx) < cnt;
          int s = __shfl(src[0], 0);          // placeholder to keep src in reg? no:
          s = src[er];                         // same addr across 16 lanes of quarter
          f32x4 bs = *reinterpret_cast<const f32x4*>(Bh_p + s * 64 + r * 4);
          f32x4 av = *reinterpret_cast<const f32x4*>(Ah_p + s * 64 + r * 4);
#pragma unroll
          for (int t = 0; t < 4; ++t) {
            float eij = acc[t][q] + cb[t] + bs[t] + bd[t];
            float re = (eij > 0.0f) ? eij : 0.0f;
            if (valid) {
              es[t] += re;
              eq[t] += re * re;
            }
            float sg = __fdividef(1.0f, 1.0f + __expf(-eij));
            float m = sg * av[t];
            m = (m > 0.0f) ? m : 0.0f;
            // padded rows duplicate a real edge of this node -> safe in max
            mreg[t] = fmaxf(mreg[t], m);
          }
        }
      }
    }
    // combine the 4 hi-groups: mreg[t] is max over this lane's rows
#pragma unroll
    for (int t = 0; t < 4; ++t) {
      mreg[t] = fmaxf(mreg[t], __shfl_xor(mreg[t], 16));
      mreg[t] = fmaxf(mreg[t], __shfl_xor(mreg[t], 32));
    }
    if (hi == 0) {
#pragma unroll
      for (int t = 0; t < 4; ++t) cbuf[node * 64 + t * 16 + r] = mreg[t];
    }
  }

  // block-level BN-stats reduction -> 1 global atomic per column per block
  if (threadIdx.x < 64) { ssum[threadIdx.x] = 0.f; ssq[threadIdx.x] = 0.f; }
  __syncthreads();
#pragma unroll
  for (int t = 0; t < 4; ++t) {
    int col = t * 16 + r;
    atomicAdd(&ssum[col], es[t]);
    atomicAdd(&ssq[col], eq[t]);
  }
  __syncthreads();
  if (threadIdx.x < 64) {
    atomicAdd(&gsum[threadIdx.x], ssum[threadIdx.x]);
    atomicAdd(&gsq[threadIdx.x], ssq[threadIdx.x]);
  }
}

// ---------------- K3: bundle = [h,c]@W_apply + b; L2-norm rows; relu ---------
__global__ void __launch_bounds__(256) k_apply(
    const float* __restrict__ h, const float* __restrict__ cbuf_f,
    const float* __restrict__ Wap, const float* __restrict__ bap,
    float* __restrict__ stage_h, float* __restrict__ gsum,
    float* __restrict__ gsq) {
  __shared__ float ssum[64], ssq[64];
  int lane = threadIdx.x & 63, warp = threadIdx.x >> 6;
  int tile = blockIdx.x * 4 + warp;
  int r = lane & 15;

  float hs[4] = {0.f, 0.f, 0.f, 0.f}, hq[4] = {0.f, 0.f, 0.f, 0.f};

  if (tile < NT_N) {
    short8 w[4][4];
    float ba[4];
#pragma unroll
    for (int t = 0; t < 4; ++t) {
#pragma unroll
      for (int kk = 0; kk < 4; ++kk) w[t][kk] = load_w_frag(Wap, kk * 32, t * 16, lane);
      ba[t] = bap[t * 16 + r];
    }

    int row0 = tile * 16;
    int ar = row0 + r, kb = (lane >> 4) * 8;
    short8 a0 = load_a_frag(h, ar, kb);
    short8 a1 = load_a_frag(h, ar, 32 + kb);
    short8 a2 = load_a_frag(cbuf_f, ar, kb);
    short8 a3 = load_a_frag(cbuf_f, ar, 32 + kb);

    f32x4 zero = {0.f, 0.f, 0.f, 0.f};
    f32x4 acc[4];
#pragma unroll
    for (int t = 0; t < 4; ++t) {
      acc[t] = mfma16(a0, w[t][0], zero);
      acc[t] = mfma16(a1, w[t][1], acc[t]);
      acc[t] = mfma16(a2, w[t][2], acc[t]);
      acc[t] = mfma16(a3, w[t][3], acc[t]);
    }

    float v[4][4];
#pragma unroll
    for (int t = 0; t < 4; ++t)
#pragma unroll
      for (int q = 0; q < 4; ++q) v[t][q] = acc[t][q] + ba[t];

#pragma unroll
    for (int q = 0; q < 4; ++q) {
      float sq = v[0][q] * v[0][q] + v[1][q] * v[1][q] + v[2][q] * v[2][q] +
                 v[3][q] * v[3][q];
      sq += __shfl_xor(sq, 1);
      sq += __shfl_xor(sq, 2);
      sq += __shfl_xor(sq, 4);
      sq += __shfl_xor(sq, 8);
      float sc = __fdividef(1.0f, fmaxf(sqrtf(sq), EPS_NORM));
      int row = row0 + (lane >> 4) * 4 + q;
#pragma unroll
      for (int t = 0; t < 4; ++t) {
        float hn = v[t][q] * sc;
        hn = (hn > 0.0f) ? hn : 0.0f;
        stage_h[row * 64 + t * 16 + r] = hn;
        hs[t] += hn;
        hq[t] += hn * hn;
      }
    }
  }

  if (threadIdx.x < 64) { ssum[threadIdx.x] = 0.f; ssq[threadIdx.x] = 0.f; }
  __syncthreads();
#pragma unroll
  for (int t = 0; t < 4; ++t) {
    int col = t * 16 + r;
    atomicAdd(&ssum[col], hs[t]);
    atomicAdd(&ssq[col], hq[t]);
  }
  __syncthreads();
  if (threadIdx.x < 64) {
    atomicAdd(&gsum[threadIdx.x], ssum[threadIdx.x]);
    atomicAdd(&gsq[threadIdx.x], ssq[threadIdx.x]);
  }
}

// ---------------- K4: fold stats into scale/offset per column ---------------
__global__ void k_stats(const float* __restrict__ sum_e, const float* __restrict__ sq_e,
                        const float* __restrict__ sum_h, const float* __restrict__ sq_h,
                        const float* __restrict__ gamma_e, const float* __restrict__ beta_e,
                        const float* __restrict__ gamma_h, const float* __restrict__ beta_h,
                        float* __restrict__ se, float* __restrict__ oe,
                        float* __restrict__ sh, float* __restrict__ oh) {
  int j = threadIdx.x;
  if (j < 64) {
    float mu = sum_e[j] / (float)NE;
    float var = fmaxf(sq_e[j] / (float)NE - mu * mu, 0.0f);
    float s = gamma_e[j] / sqrtf(var + EPS_BN);
    se[j] = s;
    oe[j] = beta_e[j] - mu * s;
    mu = sum_h[j] / (float)NN;
    var = fmaxf(sq_h[j] / (float)NN - mu * mu, 0.0f);
    s = gamma_h[j] / sqrtf(var + EPS_BN);
    sh[j] = s;
    oh[j] = beta_h[j] - mu * s;
  }
}

// ---------------- K5: h_out = h + BN(h_new)  (in place over stage) ----------
__global__ void __launch_bounds__(256) k_fin_h(const float* __restrict__ h,
                                               const float* __restrict__ sh,
                                               const float* __restrict__ oh,
                                               float* __restrict__ outh) {
  int i = (blockIdx.x * 256 + threadIdx.x) * 4;
  if (i >= NN * 64) return;
  f32x4 x = *reinterpret_cast<const f32x4*>(outh + i);
  f32x4 hv = *reinterpret_cast<const f32x4*>(h + i);
  int c0 = i & 63;
  f32x4 rr;
#pragma unroll
  for (int j = 0; j < 4; ++j) rr[j] = hv[j] + x[j] * sh[c0 + j] + oh[c0 + j];
  *reinterpret_cast<f32x4*>(outh + i) = rr;
}

// ---------------- K6: e_out = e + BN(relu(e_ij)), e_ij recomputed ------------
__global__ void __launch_bounds__(256) k_fin_e(
    const float* __restrict__ e, const int* __restrict__ src,
    const int* __restrict__ dst, const float* __restrict__ CW,
    const float* __restrict__ Cb, const float* __restrict__ Bh_p,
    const float* __restrict__ se, const float* __restrict__ oe,
    float* __restrict__ oute) {
  int lane = threadIdx.x & 63, warp = threadIdx.x >> 6;
  int r = lane & 15;

  short8 cw[4][2];
  float cb[4], sev[4], oev[4];
#pragma unroll
  for (int t = 0; t < 4; ++t) {
#pragma unroll
    for (int kk = 0; kk < 2; ++kk) cw[t][kk] = load_w_frag(CW, kk * 32, t * 16, lane);
    cb[t] = Cb[t * 16 + r];
    sev[t] = se[t * 16 + r];
    oev[t] = oe[t * 16 + r];
  }

  f32x4 zero = {0.f, 0.f, 0.f, 0.f};
  int stride = gridDim.x * 4;

  for (int tile = blockIdx.x * 4 + warp; tile < NT_E; tile += stride) {
    int e0 = tile * 16;
    int kb = (lane >> 4) * 8;
    short8 a0 = load_a_frag(e, e0 + r, kb);
    short8 a1 = load_a_frag(e, e0 + r, 32 + kb);

    f32x4 acc[4];
#pragma unroll
    for (int t = 0; t < 4; ++t) {
      acc[t] = mfma16(a0, cw[t][0], zero);
      acc[t] = mfma16(a1, cw[t][1], acc[t]);
    }

#pragma unroll
    for (int q = 0; q < 4; ++q) {
      int er = e0 + (lane >> 4) * 4 + q;
      int s = src[er], d = dst[er];
      f32x4 bs = *reinterpret_cast<const f32x4*>(Bh_p + s * 64 + r * 4);
      f32x4 bd = *reinterpret_cast<const f32x4*>(Bh_p + d * 64 + r * 4);
#pragma unroll
      for (int t = 0; t < 4; ++t) {
        float eij = acc[t][q] + cb[t] + bs[t] + bd[t];
        float re = (eij > 0.0f) ? eij : 0.0f;
        int col = t * 16 + r;
        oute[er * 64 + col] = e[er * 64 + col] + re * sev[t] + oev[t];
      }
    }
  }
}

// ---------------------------------------------------------------------------
extern "C" void kernel_launch(void* const* d_in, const int* in_sizes, int n_in,
                              void* d_out, int out_size, void* d_ws, size_t ws_size,
                              hipStream_t stream) {
  (void)in_sizes; (void)n_in; (void)out_size; (void)ws_size;
  const float* h   = (const float*)d_in[0];
  const float* e   = (const float*)d_in[1];
  const int*   src = (const int*)d_in[2];
  const int*   dst = (const int*)d_in[3];
  const float* AW  = (const float*)d_in[4];
  const float* Ab  = (const float*)d_in[5];
  const float* BW  = (const float*)d_in[6];
  const float* Bb  = (const float*)d_in[7];
  const float* CW  = (const float*)d_in[8];
  const float* Cb  = (const float*)d_in[9];
  const float* Wap = (const float*)d_in[10];
  const float* bap = (const float*)d_in[11];
  const float* gamma_h = (const float*)d_in[12];
  const float* beta_h  = (const float*)d_in[13];
  const float* gamma_e = (const float*)d_in[14];
  const float* beta_e  = (const float*)d_in[15];

  float* ws = (float*)d_ws;
  float* Ah_p = ws;                       // 3.2M floats, permuted layout
  float* Bh_p = ws + 3200000;             // 3.2M floats, permuted layout
  float* cbuf = ws + 6400000;             // 3.2M floats, natural layout
  float* stats = ws + 9600000;            // 512 floats
  float* sum_e = stats;
  float* sq_e  = stats + 64;
  float* sum_h = stats + 128;
  float* sq_h  = stats + 192;
  float* se    = stats + 256;
  float* oe    = stats + 320;
  float* sh    = stats + 384;
  float* oh    = stats + 448;

  int* deg    = (int*)(ws + 9600512);  // 50000
  int* off    = deg + NN;              // 50000
  int* bsum   = off + NN;              // 256
  int* bbase  = bsum + 256;            // 256
  int* cursor = bbase + 256;           // 50000
  int* perm   = cursor + NN;           // 800000

  float* outh = (float*)d_out;
  float* oute = outh + (size_t)NN * 64;

  k_init<<<NB_SCAN, 256, 0, stream>>>(deg, stats);
  k_deg<<<(NE + 255) / 256, 256, 0, stream>>>(dst, deg);
  k_scan_local<<<NB_SCAN, 256, 0, stream>>>(deg, off, bsum);
  k_scan_base<<<1, 256, 0, stream>>>(bsum, bbase);
  k_scan_fix<<<NB_SCAN, 256, 0, stream>>>(bbase, off, cursor);
  k_scatter<<<(NE + 255) / 256, 256, 0, stream>>>(dst, cursor, perm);

  k_node_lin<<<(NT_N + 3) / 4, 256, 0, stream>>>(h, AW, Ab, BW, Bb, Ah_p, Bh_p);
  k_edge_grouped<<<(NN + 3) / 4, 256, 0, stream>>>(e, src, deg, off, perm, CW,
                                                   Cb, Ah_p, Bh_p, cbuf,
                                                   sum_e, sq_e);
  k_apply<<<(NT_N + 3) / 4, 256, 0, stream>>>(h, cbuf, Wap, bap, outh,
                                              sum_h, sq_h);
  k_stats<<<1, 64, 0, stream>>>(sum_e, sq_e, sum_h, sq_h, gamma_e, beta_e,
                                gamma_h, beta_h, se, oe, sh, oh);
  k_fin_h<<<NN * 64 / 1024, 256, 0, stream>>>(h, sh, oh, outh);
  k_fin_e<<<2048, 256, 0, stream>>>(e, src, dst, CW, Cb, Bh_p, se, oe, oute);
}

// Round 5
// 447.770 us; speedup vs baseline: 1.4246x; 1.4246x over previous
//
#include <hip/hip_runtime.h>

typedef __attribute__((ext_vector_type(8))) short short8;
typedef __attribute__((ext_vector_type(4))) float f32x4;
typedef __attribute__((ext_vector_type(4))) unsigned int u32x4;

#define DEV static __device__ __forceinline__

constexpr int NN = 50000;       // nodes
constexpr int NE = 800000;      // edges
constexpr int NT_N = NN / 16;   // 3125 node tiles of 16 rows
constexpr int NT_E = NE / 16;   // 50000 edge tiles (NE % 16 == 0: all full)
constexpr int NB_SCAN = (NN + 255) / 256;  // 196
constexpr float EPS_BN = 1e-5f;
constexpr float EPS_NORM = 1e-12f;

// f32 -> bf16 (round-to-nearest-even)
DEV unsigned short f2b(float f) {
  unsigned u = __float_as_uint(f);
  return (unsigned short)((u + 0x7FFFu + ((u >> 16) & 1u)) >> 16);
}

// A-fragment for mfma_f32_16x16x32_bf16 from a row-major [*][64] f32 matrix.
// lane (hi,r) holds row chosen per-lane, k = kbase + j (j=0..7)
DEV short8 load_a_frag(const float* __restrict__ base, int row, int kbase) {
  const f32x4* p = reinterpret_cast<const f32x4*>(base + row * 64 + kbase);
  f32x4 v0 = p[0], v1 = p[1];
  short8 a;
  a[0] = f2b(v0[0]); a[1] = f2b(v0[1]); a[2] = f2b(v0[2]); a[3] = f2b(v0[3]);
  a[4] = f2b(v1[0]); a[5] = f2b(v1[1]); a[6] = f2b(v1[2]); a[7] = f2b(v1[3]);
  return a;
}

// B-fragment: W is [K][64] row-major f32.
DEV short8 load_w_frag(const float* __restrict__ W, int kbase, int c0, int lane) {
  int kr = kbase + ((lane >> 4) << 3);
  int cc = c0 + (lane & 15);
  short8 b;
#pragma unroll
  for (int j = 0; j < 8; ++j) b[j] = f2b(W[(kr + j) * 64 + cc]);
  return b;
}

DEV f32x4 mfma16(short8 a, short8 b, f32x4 c) {
  return __builtin_amdgcn_mfma_f32_16x16x32_bf16(a, b, c, 0, 0, 0);
}

// ---------------- init: zero cbuf + deg + stats ------------------------------
__global__ void k_init(u32x4* __restrict__ cbuf4, int* __restrict__ deg,
                       float* __restrict__ stats) {
  int i = blockIdx.x * 256 + threadIdx.x;  // grid = 3125*256 = 800000 = NN*64/4
  u32x4 z = {0u, 0u, 0u, 0u};
  cbuf4[i] = z;
  if (i < NN) deg[i] = 0;
  if (i < 512) stats[i] = 0.0f;
}

// ---------------- CSR build -------------------------------------------------
__global__ void k_deg(const int* __restrict__ dst, int* __restrict__ deg) {
  int i = blockIdx.x * 256 + threadIdx.x;
  if (i < NE) atomicAdd(&deg[dst[i]], 1);
}

__global__ void k_scan_local(const int* __restrict__ deg, int* __restrict__ off,
                             int* __restrict__ bsum) {
  __shared__ int sh[256];
  int t = threadIdx.x;
  int i = blockIdx.x * 256 + t;
  int v = (i < NN) ? deg[i] : 0;
  sh[t] = v;
  __syncthreads();
  for (int s = 1; s < 256; s <<= 1) {
    int u = (t >= s) ? sh[t - s] : 0;
    __syncthreads();
    sh[t] += u;
    __syncthreads();
  }
  if (i < NN) off[i] = sh[t] - v;
  if (t == 255) bsum[blockIdx.x] = sh[255];
}

__global__ void k_scan_base(const int* __restrict__ bsum, int* __restrict__ bbase) {
  __shared__ int sh[256];
  int t = threadIdx.x;
  int v = (t < NB_SCAN) ? bsum[t] : 0;
  sh[t] = v;
  __syncthreads();
  for (int s = 1; s < 256; s <<= 1) {
    int u = (t >= s) ? sh[t - s] : 0;
    __syncthreads();
    sh[t] += u;
    __syncthreads();
  }
  if (t < NB_SCAN) bbase[t] = sh[t] - v;
}

__global__ void k_scan_fix(const int* __restrict__ bbase, int* __restrict__ off,
                           int* __restrict__ cursor) {
  int i = blockIdx.x * 256 + threadIdx.x;
  if (i < NN) {
    int o = off[i] + bbase[blockIdx.x];
    off[i] = o;
    cursor[i] = o;
  }
}

__global__ void k_scatter(const int* __restrict__ dst, int* __restrict__ cursor,
                          int* __restrict__ perm) {
  int i = blockIdx.x * 256 + threadIdx.x;
  if (i < NE) {
    int p = atomicAdd(&cursor[dst[i]], 1);
    perm[p] = i;
  }
}

// ---------------- K1: Ah_p/Bh_p = (h@A_W+A_b, h@B_W+B_b), permuted layout ----
// Permuted layout: value for column c = t*16+r stored at [node*64 + r*4 + t].
__global__ void __launch_bounds__(256) k_node_lin(
    const float* __restrict__ h, const float* __restrict__ AW,
    const float* __restrict__ Ab, const float* __restrict__ BW,
    const float* __restrict__ Bb, float* __restrict__ Ah_p,
    float* __restrict__ Bh_p) {
  int lane = threadIdx.x & 63, warp = threadIdx.x >> 6;
  int tile = blockIdx.x * 4 + warp;
  if (tile >= NT_N) return;
  int r = lane & 15;

  short8 wa[4][2], wb[4][2];
  float ab[4], bb[4];
#pragma unroll
  for (int t = 0; t < 4; ++t) {
#pragma unroll
    for (int kk = 0; kk < 2; ++kk) {
      wa[t][kk] = load_w_frag(AW, kk * 32, t * 16, lane);
      wb[t][kk] = load_w_frag(BW, kk * 32, t * 16, lane);
    }
    ab[t] = Ab[t * 16 + r];
    bb[t] = Bb[t * 16 + r];
  }

  int row0 = tile * 16;
  int ar = row0 + r, kb = (lane >> 4) * 8;
  short8 a0 = load_a_frag(h, ar, kb);
  short8 a1 = load_a_frag(h, ar, 32 + kb);

  f32x4 zero = {0.f, 0.f, 0.f, 0.f};
  f32x4 accA[4], accB[4];
#pragma unroll
  for (int t = 0; t < 4; ++t) {
    accA[t] = mfma16(a0, wa[t][0], zero);
    accA[t] = mfma16(a1, wa[t][1], accA[t]);
    accB[t] = mfma16(a0, wb[t][0], zero);
    accB[t] = mfma16(a1, wb[t][1], accB[t]);
  }
#pragma unroll
  for (int q = 0; q < 4; ++q) {
    int row = row0 + (lane >> 4) * 4 + q;
    f32x4 va = {accA[0][q] + ab[0], accA[1][q] + ab[1], accA[2][q] + ab[2],
                accA[3][q] + ab[3]};
    f32x4 vb = {accB[0][q] + bb[0], accB[1][q] + bb[1], accB[2][q] + bb[2],
                accB[3][q] + bb[3]};
    *reinterpret_cast<f32x4*>(Ah_p + row * 64 + r * 4) = va;
    *reinterpret_cast<f32x4*>(Bh_p + row * 64 + r * 4) = vb;
  }
}

// ---------------- K2: perm-tile edge pass (dst-sorted, few atomics) ----------
// Grid-stride over 50k full tiles of 16 perm-ordered edges. Per tile:
//   e_ij = e[perm]@C_W + C_b + Bh[src] + Bh[dst]   (MFMA)
//   BN stats of relu(e_ij) (no masking: all tiles full)
//   msg = relu(sigmoid(e_ij)*Ah[src]) -> LDS transpose -> 16-row segmented
//   scan: interior runs plain-store c[node], boundary runs atomicMax.
__global__ void __launch_bounds__(256) k_edge_sorted(
    const float* __restrict__ e, const int* __restrict__ src,
    const int* __restrict__ dst, const int* __restrict__ perm,
    const float* __restrict__ CW, const float* __restrict__ Cb,
    const float* __restrict__ Ah_p, const float* __restrict__ Bh_p,
    float* __restrict__ cbuf, float* __restrict__ gsum,
    float* __restrict__ gsq) {
  __shared__ float msgT[4][64 * 17];  // per-wave: [col][row], stride 17
  __shared__ float ssum[64], ssq[64];
  int lane = threadIdx.x & 63, warp = threadIdx.x >> 6;
  int r = lane & 15, hi = lane >> 4;
  float* mT = msgT[warp];

  short8 cw[4][2];
  float cb4[4];
#pragma unroll
  for (int t = 0; t < 4; ++t) {
#pragma unroll
    for (int kk = 0; kk < 2; ++kk) cw[t][kk] = load_w_frag(CW, kk * 32, t * 16, lane);
    cb4[t] = Cb[t * 16 + r];
  }

  float es[4] = {0.f, 0.f, 0.f, 0.f}, eq[4] = {0.f, 0.f, 0.f, 0.f};
  f32x4 zero = {0.f, 0.f, 0.f, 0.f};
  int stride = gridDim.x * 4;

  for (int tile = blockIdx.x * 4 + warp; tile < NT_E; tile += stride) {
    // every lane loads its row's identifiers (4x dup across hi -> broadcast)
    int p = perm[tile * 16 + r];
    int d = dst[p];
    int s = src[p];

    int kb = hi * 8;
    short8 a0 = load_a_frag(e, p, kb);
    short8 a1 = load_a_frag(e, p, 32 + kb);

    f32x4 acc[4];
#pragma unroll
    for (int t = 0; t < 4; ++t) {
      acc[t] = mfma16(a0, cw[t][0], zero);
      acc[t] = mfma16(a1, cw[t][1], acc[t]);
    }

#pragma unroll
    for (int q = 0; q < 4; ++q) {
      int rowidx = hi * 4 + q;
      int sq_ = __shfl(s, rowidx);
      int dq_ = __shfl(d, rowidx);
      f32x4 bs = *reinterpret_cast<const f32x4*>(Bh_p + sq_ * 64 + r * 4);
      f32x4 bd = *reinterpret_cast<const f32x4*>(Bh_p + dq_ * 64 + r * 4);
      f32x4 av = *reinterpret_cast<const f32x4*>(Ah_p + sq_ * 64 + r * 4);
#pragma unroll
      for (int t = 0; t < 4; ++t) {
        float eij = acc[t][q] + cb4[t] + bs[t] + bd[t];
        float re = (eij > 0.0f) ? eij : 0.0f;
        es[t] += re;
        eq[t] += re * re;
        float sg = __fdividef(1.0f, 1.0f + __expf(-eij));
        float m = sg * av[t];
        m = (m > 0.0f) ? m : 0.0f;  // canonical +0
        mT[(t * 16 + r) * 17 + rowidx] = m;
      }
    }

    // segmented max scan over the 16 rows; lane = column
    float cur = mT[lane * 17 + 0];
    int cur_d = __shfl(d, 0);
    int run_start = 0;
#pragma unroll
    for (int row = 1; row < 16; ++row) {
      float val = mT[lane * 17 + row];
      int dr = __shfl(d, row);
      if (dr == cur_d) {
        cur = fmaxf(cur, val);
      } else {
        // run ended at row-1 (<15). Interior iff it started after row 0.
        if (run_start == 0)
          atomicMax((unsigned*)&cbuf[cur_d * 64 + lane], __float_as_uint(cur));
        else
          cbuf[cur_d * 64 + lane] = cur;
        cur_d = dr;
        cur = val;
        run_start = row;
      }
    }
    // last run touches the tile end -> may continue in next tile
    atomicMax((unsigned*)&cbuf[cur_d * 64 + lane], __float_as_uint(cur));
  }

  // block-level BN-stats reduction -> 1 global atomic per column per block
  if (threadIdx.x < 64) { ssum[threadIdx.x] = 0.f; ssq[threadIdx.x] = 0.f; }
  __syncthreads();
#pragma unroll
  for (int t = 0; t < 4; ++t) {
    int col = t * 16 + r;
    atomicAdd(&ssum[col], es[t]);
    atomicAdd(&ssq[col], eq[t]);
  }
  __syncthreads();
  if (threadIdx.x < 64) {
    atomicAdd(&gsum[threadIdx.x], ssum[threadIdx.x]);
    atomicAdd(&gsq[threadIdx.x], ssq[threadIdx.x]);
  }
}

// ---------------- K3: bundle = [h,c]@W_apply + b; L2-norm rows; relu ---------
__global__ void __launch_bounds__(256) k_apply(
    const float* __restrict__ h, const float* __restrict__ cbuf_f,
    const float* __restrict__ Wap, const float* __restrict__ bap,
    float* __restrict__ stage_h, float* __restrict__ gsum,
    float* __restrict__ gsq) {
  __shared__ float ssum[64], ssq[64];
  int lane = threadIdx.x & 63, warp = threadIdx.x >> 6;
  int tile = blockIdx.x * 4 + warp;
  int r = lane & 15;

  float hs[4] = {0.f, 0.f, 0.f, 0.f}, hq[4] = {0.f, 0.f, 0.f, 0.f};

  if (tile < NT_N) {
    short8 w[4][4];
    float ba[4];
#pragma unroll
    for (int t = 0; t < 4; ++t) {
#pragma unroll
      for (int kk = 0; kk < 4; ++kk) w[t][kk] = load_w_frag(Wap, kk * 32, t * 16, lane);
      ba[t] = bap[t * 16 + r];
    }

    int row0 = tile * 16;
    int ar = row0 + r, kb = (lane >> 4) * 8;
    short8 a0 = load_a_frag(h, ar, kb);
    short8 a1 = load_a_frag(h, ar, 32 + kb);
    short8 a2 = load_a_frag(cbuf_f, ar, kb);
    short8 a3 = load_a_frag(cbuf_f, ar, 32 + kb);

    f32x4 zero = {0.f, 0.f, 0.f, 0.f};
    f32x4 acc[4];
#pragma unroll
    for (int t = 0; t < 4; ++t) {
      acc[t] = mfma16(a0, w[t][0], zero);
      acc[t] = mfma16(a1, w[t][1], acc[t]);
      acc[t] = mfma16(a2, w[t][2], acc[t]);
      acc[t] = mfma16(a3, w[t][3], acc[t]);
    }

    float v[4][4];
#pragma unroll
    for (int t = 0; t < 4; ++t)
#pragma unroll
      for (int q = 0; q < 4; ++q) v[t][q] = acc[t][q] + ba[t];

#pragma unroll
    for (int q = 0; q < 4; ++q) {
      float sq = v[0][q] * v[0][q] + v[1][q] * v[1][q] + v[2][q] * v[2][q] +
                 v[3][q] * v[3][q];
      sq += __shfl_xor(sq, 1);
      sq += __shfl_xor(sq, 2);
      sq += __shfl_xor(sq, 4);
      sq += __shfl_xor(sq, 8);
      float sc = __fdividef(1.0f, fmaxf(sqrtf(sq), EPS_NORM));
      int row = row0 + (lane >> 4) * 4 + q;
#pragma unroll
      for (int t = 0; t < 4; ++t) {
        float hn = v[t][q] * sc;
        hn = (hn > 0.0f) ? hn : 0.0f;
        stage_h[row * 64 + t * 16 + r] = hn;
        hs[t] += hn;
        hq[t] += hn * hn;
      }
    }
  }

  if (threadIdx.x < 64) { ssum[threadIdx.x] = 0.f; ssq[threadIdx.x] = 0.f; }
  __syncthreads();
#pragma unroll
  for (int t = 0; t < 4; ++t) {
    int col = t * 16 + r;
    atomicAdd(&ssum[col], hs[t]);
    atomicAdd(&ssq[col], hq[t]);
  }
  __syncthreads();
  if (threadIdx.x < 64) {
    atomicAdd(&gsum[threadIdx.x], ssum[threadIdx.x]);
    atomicAdd(&gsq[threadIdx.x], ssq[threadIdx.x]);
  }
}

// ---------------- K4: fold stats into scale/offset per column ---------------
__global__ void k_stats(const float* __restrict__ sum_e, const float* __restrict__ sq_e,
                        const float* __restrict__ sum_h, const float* __restrict__ sq_h,
                        const float* __restrict__ gamma_e, const float* __restrict__ beta_e,
                        const float* __restrict__ gamma_h, const float* __restrict__ beta_h,
                        float* __restrict__ se, float* __restrict__ oe,
                        float* __restrict__ sh, float* __restrict__ oh) {
  int j = threadIdx.x;
  if (j < 64) {
    float mu = sum_e[j] / (float)NE;
    float var = fmaxf(sq_e[j] / (float)NE - mu * mu, 0.0f);
    float s = gamma_e[j] / sqrtf(var + EPS_BN);
    se[j] = s;
    oe[j] = beta_e[j] - mu * s;
    mu = sum_h[j] / (float)NN;
    var = fmaxf(sq_h[j] / (float)NN - mu * mu, 0.0f);
    s = gamma_h[j] / sqrtf(var + EPS_BN);
    sh[j] = s;
    oh[j] = beta_h[j] - mu * s;
  }
}

// ---------------- K5: h_out = h + BN(h_new)  (in place over stage) ----------
__global__ void __launch_bounds__(256) k_fin_h(const float* __restrict__ h,
                                               const float* __restrict__ sh,
                                               const float* __restrict__ oh,
                                               float* __restrict__ outh) {
  int i = (blockIdx.x * 256 + threadIdx.x) * 4;
  if (i >= NN * 64) return;
  f32x4 x = *reinterpret_cast<const f32x4*>(outh + i);
  f32x4 hv = *reinterpret_cast<const f32x4*>(h + i);
  int c0 = i & 63;
  f32x4 rr;
#pragma unroll
  for (int j = 0; j < 4; ++j) rr[j] = hv[j] + x[j] * sh[c0 + j] + oh[c0 + j];
  *reinterpret_cast<f32x4*>(outh + i) = rr;
}

// ---------------- K6: e_out = e + BN(relu(e_ij)), e_ij recomputed ------------
__global__ void __launch_bounds__(256) k_fin_e(
    const float* __restrict__ e, const int* __restrict__ src,
    const int* __restrict__ dst, const float* __restrict__ CW,
    const float* __restrict__ Cb, const float* __restrict__ Bh_p,
    const float* __restrict__ se, const float* __restrict__ oe,
    float* __restrict__ oute) {
  int lane = threadIdx.x & 63, warp = threadIdx.x >> 6;
  int r = lane & 15;

  short8 cw[4][2];
  float cb[4], sev[4], oev[4];
#pragma unroll
  for (int t = 0; t < 4; ++t) {
#pragma unroll
    for (int kk = 0; kk < 2; ++kk) cw[t][kk] = load_w_frag(CW, kk * 32, t * 16, lane);
    cb[t] = Cb[t * 16 + r];
    sev[t] = se[t * 16 + r];
    oev[t] = oe[t * 16 + r];
  }

  f32x4 zero = {0.f, 0.f, 0.f, 0.f};
  int stride = gridDim.x * 4;

  for (int tile = blockIdx.x * 4 + warp; tile < NT_E; tile += stride) {
    int e0 = tile * 16;
    int kb = (lane >> 4) * 8;
    short8 a0 = load_a_frag(e, e0 + r, kb);
    short8 a1 = load_a_frag(e, e0 + r, 32 + kb);

    f32x4 acc[4];
#pragma unroll
    for (int t = 0; t < 4; ++t) {
      acc[t] = mfma16(a0, cw[t][0], zero);
      acc[t] = mfma16(a1, cw[t][1], acc[t]);
    }

#pragma unroll
    for (int q = 0; q < 4; ++q) {
      int er = e0 + (lane >> 4) * 4 + q;
      int s = src[er], d = dst[er];
      f32x4 bs = *reinterpret_cast<const f32x4*>(Bh_p + s * 64 + r * 4);
      f32x4 bd = *reinterpret_cast<const f32x4*>(Bh_p + d * 64 + r * 4);
#pragma unroll
      for (int t = 0; t < 4; ++t) {
        float eij = acc[t][q] + cb[t] + bs[t] + bd[t];
        float re = (eij > 0.0f) ? eij : 0.0f;
        int col = t * 16 + r;
        oute[er * 64 + col] = e[er * 64 + col] + re * sev[t] + oev[t];
      }
    }
  }
}

// ---------------------------------------------------------------------------
extern "C" void kernel_launch(void* const* d_in, const int* in_sizes, int n_in,
                              void* d_out, int out_size, void* d_ws, size_t ws_size,
                              hipStream_t stream) {
  (void)in_sizes; (void)n_in; (void)out_size; (void)ws_size;
  const float* h   = (const float*)d_in[0];
  const float* e   = (const float*)d_in[1];
  const int*   src = (const int*)d_in[2];
  const int*   dst = (const int*)d_in[3];
  const float* AW  = (const float*)d_in[4];
  const float* Ab  = (const float*)d_in[5];
  const float* BW  = (const float*)d_in[6];
  const float* Bb  = (const float*)d_in[7];
  const float* CW  = (const float*)d_in[8];
  const float* Cb  = (const float*)d_in[9];
  const float* Wap = (const float*)d_in[10];
  const float* bap = (const float*)d_in[11];
  const float* gamma_h = (const float*)d_in[12];
  const float* beta_h  = (const float*)d_in[13];
  const float* gamma_e = (const float*)d_in[14];
  const float* beta_e  = (const float*)d_in[15];

  float* ws = (float*)d_ws;
  float* Ah_p = ws;                       // 3.2M floats, permuted layout
  float* Bh_p = ws + 3200000;             // 3.2M floats, permuted layout
  float* cbuf = ws + 6400000;             // 3.2M floats, natural layout
  float* stats = ws + 9600000;            // 512 floats
  float* sum_e = stats;
  float* sq_e  = stats + 64;
  float* sum_h = stats + 128;
  float* sq_h  = stats + 192;
  float* se    = stats + 256;
  float* oe    = stats + 320;
  float* sh    = stats + 384;
  float* oh    = stats + 448;

  int* deg    = (int*)(ws + 9600512);  // 50000
  int* off    = deg + NN;              // 50000
  int* bsum   = off + NN;              // 256
  int* bbase  = bsum + 256;            // 256
  int* cursor = bbase + 256;           // 50000
  int* perm   = cursor + NN;           // 800000

  float* outh = (float*)d_out;
  float* oute = outh + (size_t)NN * 64;

  k_init<<<3125, 256, 0, stream>>>((u32x4*)cbuf, deg, stats);
  k_deg<<<(NE + 255) / 256, 256, 0, stream>>>(dst, deg);
  k_scan_local<<<NB_SCAN, 256, 0, stream>>>(deg, off, bsum);
  k_scan_base<<<1, 256, 0, stream>>>(bsum, bbase);
  k_scan_fix<<<NB_SCAN, 256, 0, stream>>>(bbase, off, cursor);
  k_scatter<<<(NE + 255) / 256, 256, 0, stream>>>(dst, cursor, perm);

  k_node_lin<<<(NT_N + 3) / 4, 256, 0, stream>>>(h, AW, Ab, BW, Bb, Ah_p, Bh_p);
  k_edge_sorted<<<2048, 256, 0, stream>>>(e, src, dst, perm, CW, Cb, Ah_p,
                                          Bh_p, cbuf, sum_e, sq_e);
  k_apply<<<(NT_N + 3) / 4, 256, 0, stream>>>(h, cbuf, Wap, bap, outh,
                                              sum_h, sq_h);
  k_stats<<<1, 64, 0, stream>>>(sum_e, sq_e, sum_h, sq_h, gamma_e, beta_e,
                                gamma_h, beta_h, se, oe, sh, oh);
  k_fin_h<<<NN * 64 / 1024, 256, 0, stream>>>(h, sh, oh, outh);
  k_fin_e<<<2048, 256, 0, stream>>>(e, src, dst, CW, Cb, Bh_p, se, oe, oute);
}

// Round 6
// 420.913 us; speedup vs baseline: 1.5156x; 1.0638x over previous
//
#include <hip/hip_runtime.h>

typedef __attribute__((ext_vector_type(8))) short short8;
typedef __attribute__((ext_vector_type(8))) unsigned short ushort8;
typedef __attribute__((ext_vector_type(4))) float f32x4;
typedef __attribute__((ext_vector_type(4))) unsigned int u32x4;

#define DEV static __device__ __forceinline__

constexpr int NN = 50000;       // nodes
constexpr int NE = 800000;      // edges
constexpr int NT_N = NN / 16;   // 3125 node tiles of 16 rows
constexpr int NT_E = NE / 16;   // 50000 edge tiles (NE % 16 == 0: all full)
constexpr int NB_SCAN = (NN + 255) / 256;  // 196
constexpr float EPS_BN = 1e-5f;
constexpr float EPS_NORM = 1e-12f;

// f32 -> bf16 (round-to-nearest-even)
DEV unsigned short f2b(float f) {
  unsigned u = __float_as_uint(f);
  return (unsigned short)((u + 0x7FFFu + ((u >> 16) & 1u)) >> 16);
}
DEV float b2f(unsigned short s) { return __uint_as_float(((unsigned)s) << 16); }

// A-fragment for mfma_f32_16x16x32_bf16 from a row-major [*][64] f32 matrix.
DEV short8 load_a_frag(const float* __restrict__ base, int row, int kbase) {
  const f32x4* p = reinterpret_cast<const f32x4*>(base + row * 64 + kbase);
  f32x4 v0 = p[0], v1 = p[1];
  short8 a;
  a[0] = f2b(v0[0]); a[1] = f2b(v0[1]); a[2] = f2b(v0[2]); a[3] = f2b(v0[3]);
  a[4] = f2b(v1[0]); a[5] = f2b(v1[1]); a[6] = f2b(v1[2]); a[7] = f2b(v1[3]);
  return a;
}

// B-fragment: W is [K][64] row-major f32.
DEV short8 load_w_frag(const float* __restrict__ W, int kbase, int c0, int lane) {
  int kr = kbase + ((lane >> 4) << 3);
  int cc = c0 + (lane & 15);
  short8 b;
#pragma unroll
  for (int j = 0; j < 8; ++j) b[j] = f2b(W[(kr + j) * 64 + cc]);
  return b;
}

DEV f32x4 mfma16(short8 a, short8 b, f32x4 c) {
  return __builtin_amdgcn_mfma_f32_16x16x32_bf16(a, b, c, 0, 0, 0);
}

// ---------------- init: zero cbuf (+0.0f) + deg + stats ----------------------
__global__ void k_init(u32x4* __restrict__ cbuf4, int* __restrict__ deg,
                       float* __restrict__ stats) {
  int i = blockIdx.x * 256 + threadIdx.x;  // grid 3125*256 = 800000 = NN*64/4
  u32x4 z = {0u, 0u, 0u, 0u};
  cbuf4[i] = z;
  if (i < NN) deg[i] = 0;
  if (i < 512) stats[i] = 0.0f;
}

// ---------------- CSR build -------------------------------------------------
__global__ void k_deg(const int* __restrict__ dst, int* __restrict__ deg) {
  int i = blockIdx.x * 256 + threadIdx.x;
  if (i < NE) atomicAdd(&deg[dst[i]], 1);
}

__global__ void k_scan_local(const int* __restrict__ deg, int* __restrict__ off,
                             int* __restrict__ bsum) {
  __shared__ int sh[256];
  int t = threadIdx.x;
  int i = blockIdx.x * 256 + t;
  int v = (i < NN) ? deg[i] : 0;
  sh[t] = v;
  __syncthreads();
  for (int s = 1; s < 256; s <<= 1) {
    int u = (t >= s) ? sh[t - s] : 0;
    __syncthreads();
    sh[t] += u;
    __syncthreads();
  }
  if (i < NN) off[i] = sh[t] - v;
  if (t == 255) bsum[blockIdx.x] = sh[255];
}

__global__ void k_scan_base(const int* __restrict__ bsum, int* __restrict__ bbase) {
  __shared__ int sh[256];
  int t = threadIdx.x;
  int v = (t < NB_SCAN) ? bsum[t] : 0;
  sh[t] = v;
  __syncthreads();
  for (int s = 1; s < 256; s <<= 1) {
    int u = (t >= s) ? sh[t - s] : 0;
    __syncthreads();
    sh[t] += u;
    __syncthreads();
  }
  if (t < NB_SCAN) bbase[t] = sh[t] - v;
}

__global__ void k_scan_fix(const int* __restrict__ bbase, int* __restrict__ off,
                           int* __restrict__ cursor) {
  int i = blockIdx.x * 256 + threadIdx.x;
  if (i < NN) {
    int o = off[i] + bbase[blockIdx.x];
    off[i] = o;
    cursor[i] = o;
  }
}

__global__ void k_scatter(const int* __restrict__ dst, int* __restrict__ cursor,
                          int* __restrict__ perm) {
  int i = blockIdx.x * 256 + threadIdx.x;
  if (i < NE) {
    int p = atomicAdd(&cursor[dst[i]], 1);
    perm[p] = i;
  }
}

// ---------------- K1: Ah_p/Bh_p = (h@A_W+A_b, h@B_W+B_b), permuted layout ----
// Permuted layout: value for column c = t*16+r stored at [node*64 + r*4 + t].
__global__ void __launch_bounds__(256) k_node_lin(
    const float* __restrict__ h, const float* __restrict__ AW,
    const float* __restrict__ Ab, const float* __restrict__ BW,
    const float* __restrict__ Bb, float* __restrict__ Ah_p,
    float* __restrict__ Bh_p) {
  int lane = threadIdx.x & 63, warp = threadIdx.x >> 6;
  int tile = blockIdx.x * 4 + warp;
  if (tile >= NT_N) return;
  int r = lane & 15;

  short8 wa[4][2], wb[4][2];
  float ab[4], bb[4];
#pragma unroll
  for (int t = 0; t < 4; ++t) {
#pragma unroll
    for (int kk = 0; kk < 2; ++kk) {
      wa[t][kk] = load_w_frag(AW, kk * 32, t * 16, lane);
      wb[t][kk] = load_w_frag(BW, kk * 32, t * 16, lane);
    }
    ab[t] = Ab[t * 16 + r];
    bb[t] = Bb[t * 16 + r];
  }

  int row0 = tile * 16;
  int ar = row0 + r, kb = (lane >> 4) * 8;
  short8 a0 = load_a_frag(h, ar, kb);
  short8 a1 = load_a_frag(h, ar, 32 + kb);

  f32x4 zero = {0.f, 0.f, 0.f, 0.f};
  f32x4 accA[4], accB[4];
#pragma unroll
  for (int t = 0; t < 4; ++t) {
    accA[t] = mfma16(a0, wa[t][0], zero);
    accA[t] = mfma16(a1, wa[t][1], accA[t]);
    accB[t] = mfma16(a0, wb[t][0], zero);
    accB[t] = mfma16(a1, wb[t][1], accB[t]);
  }
#pragma unroll
  for (int q = 0; q < 4; ++q) {
    int row = row0 + (lane >> 4) * 4 + q;
    f32x4 va = {accA[0][q] + ab[0], accA[1][q] + ab[1], accA[2][q] + ab[2],
                accA[3][q] + ab[3]};
    f32x4 vb = {accB[0][q] + bb[0], accB[1][q] + bb[1], accB[2][q] + bb[2],
                accB[3][q] + bb[3]};
    *reinterpret_cast<f32x4*>(Ah_p + row * 64 + r * 4) = va;
    *reinterpret_cast<f32x4*>(Bh_p + row * 64 + r * 4) = vb;
  }
}

// ---------------- K2: perm-tile edge pass (dst-sorted) -----------------------
// Per 16-edge tile: e_ij via MFMA (+Bh gathers), BN stats, stage e_ij bf16
// (LDS repack -> full-row 16B stores), msg -> bf16 LDS transpose -> segmented
// max scan (interior runs plain-store, boundary runs atomicMax).
__global__ void __launch_bounds__(256) k_edge_sorted(
    const float* __restrict__ e, const int* __restrict__ src,
    const int* __restrict__ dst, const int* __restrict__ perm,
    const float* __restrict__ CW, const float* __restrict__ Cb,
    const float* __restrict__ Ah_p, const float* __restrict__ Bh_p,
    float* __restrict__ cbuf, unsigned short* __restrict__ stage,
    float* __restrict__ gsum, float* __restrict__ gsq) {
  __shared__ short8 cwL[8][64];                       // 8 KB, shared by block
  __shared__ unsigned short mT[4][64][18];            // 9.2 KB msg transpose
  __shared__ __align__(16) unsigned short eT[4][16][72];  // 9.2 KB e_ij rows
  __shared__ float ssum[64], ssq[64];
  int lane = threadIdx.x & 63, warp = threadIdx.x >> 6;
  int r = lane & 15, hi = lane >> 4;

  // one weight-fragment copy per block
  for (int j = threadIdx.x; j < 512; j += 256) {
    int t = j >> 7, kk = (j >> 6) & 1, ln = j & 63;
    cwL[t * 2 + kk][ln] = load_w_frag(CW, kk * 32, t * 16, ln);
  }
  float cb4[4];
#pragma unroll
  for (int t = 0; t < 4; ++t) cb4[t] = Cb[t * 16 + r];
  __syncthreads();

  unsigned short (*mTw)[18] = mT[warp];
  unsigned short (*eTw)[72] = eT[warp];

  float es[4] = {0.f, 0.f, 0.f, 0.f}, eq[4] = {0.f, 0.f, 0.f, 0.f};
  f32x4 zero = {0.f, 0.f, 0.f, 0.f};
  int stride = gridDim.x * 4;
  int tile0 = blockIdx.x * 4 + warp;

  int p = 0;
  if (tile0 < NT_E) p = perm[tile0 * 16 + r];

  for (int tile = tile0; tile < NT_E; tile += stride) {
    int tn = tile + stride;
    int p_next = 0, d, s;
    if (tn < NT_E) p_next = perm[tn * 16 + r];   // prefetch next ids
    d = dst[p];
    s = src[p];

    int kb = hi * 8;
    short8 a0 = load_a_frag(e, p, kb);
    short8 a1 = load_a_frag(e, p, 32 + kb);

    f32x4 acc[4];
#pragma unroll
    for (int t = 0; t < 4; ++t) {
      acc[t] = mfma16(a0, cwL[t * 2][lane], zero);
      acc[t] = mfma16(a1, cwL[t * 2 + 1][lane], acc[t]);
    }

#pragma unroll
    for (int q = 0; q < 4; ++q) {
      int rowidx = hi * 4 + q;
      int sq_ = __shfl(s, rowidx);
      int dq_ = __shfl(d, rowidx);
      f32x4 bs = *reinterpret_cast<const f32x4*>(Bh_p + sq_ * 64 + r * 4);
      f32x4 bd = *reinterpret_cast<const f32x4*>(Bh_p + dq_ * 64 + r * 4);
      f32x4 av = *reinterpret_cast<const f32x4*>(Ah_p + sq_ * 64 + r * 4);
#pragma unroll
      for (int t = 0; t < 4; ++t) {
        float eij = acc[t][q] + cb4[t] + bs[t] + bd[t];
        float re = (eij > 0.0f) ? eij : 0.0f;
        es[t] += re;
        eq[t] += re * re;
        eTw[rowidx][t * 16 + r] = f2b(eij);
        float sg = __fdividef(1.0f, 1.0f + __expf(-eij));
        float m = sg * av[t];
        m = (m > 0.0f) ? m : 0.0f;  // canonical +0
        mTw[t * 16 + r][rowidx] = f2b(m);
      }
    }
    __builtin_amdgcn_sched_barrier(0);  // keep LDS transpose writes before reads

    // stage writeout: 16 rows x 128B via two 16B stores per lane
#pragma unroll
    for (int it = 0; it < 2; ++it) {
      int row = (lane >> 3) + it * 8;
      int seg = lane & 7;
      int er = __shfl(p, row);
      ushort8 v = *reinterpret_cast<const ushort8*>(&eTw[row][seg * 8]);
      *reinterpret_cast<ushort8*>(stage + (size_t)er * 64 + seg * 8) = v;
    }

    // segmented max scan over the 16 rows; lane = column (bf16 u16 compare:
    // monotone for nonneg bf16 bit patterns)
    unsigned short cur = mTw[lane][0];
    int cur_d = __shfl(d, 0);
    int run_start = 0;
#pragma unroll
    for (int row = 1; row < 16; ++row) {
      unsigned short val = mTw[lane][row];
      int dr = __shfl(d, row);
      if (dr == cur_d) {
        cur = (val > cur) ? val : cur;
      } else {
        float cf = b2f(cur);
        if (run_start == 0)
          atomicMax((unsigned*)&cbuf[cur_d * 64 + lane], __float_as_uint(cf));
        else
          cbuf[cur_d * 64 + lane] = cf;
        cur_d = dr;
        cur = val;
        run_start = row;
      }
    }
    atomicMax((unsigned*)&cbuf[cur_d * 64 + lane], __float_as_uint(b2f(cur)));

    p = p_next;
  }

  // block-level BN-stats reduction -> 1 global atomic per column per block
  if (threadIdx.x < 64) { ssum[threadIdx.x] = 0.f; ssq[threadIdx.x] = 0.f; }
  __syncthreads();
#pragma unroll
  for (int t = 0; t < 4; ++t) {
    int col = t * 16 + r;
    atomicAdd(&ssum[col], es[t]);
    atomicAdd(&ssq[col], eq[t]);
  }
  __syncthreads();
  if (threadIdx.x < 64) {
    atomicAdd(&gsum[threadIdx.x], ssum[threadIdx.x]);
    atomicAdd(&gsq[threadIdx.x], ssq[threadIdx.x]);
  }
}

// ---------------- K3: bundle = [h,c]@W_apply + b; L2-norm rows; relu ---------
// hc == d_out h-region: rows are READ as c (cbuf) then WRITTEN as stage_h.
// Same rows per wave; loads precede stores in program order -> safe.
__global__ void __launch_bounds__(256) k_apply(
    const float* __restrict__ h, float* hc, const float* __restrict__ Wap,
    const float* __restrict__ bap, float* __restrict__ gsum,
    float* __restrict__ gsq) {
  __shared__ float ssum[64], ssq[64];
  int lane = threadIdx.x & 63, warp = threadIdx.x >> 6;
  int tile = blockIdx.x * 4 + warp;
  int r = lane & 15;

  float hs[4] = {0.f, 0.f, 0.f, 0.f}, hq[4] = {0.f, 0.f, 0.f, 0.f};

  if (tile < NT_N) {
    short8 w[4][4];
    float ba[4];
#pragma unroll
    for (int t = 0; t < 4; ++t) {
#pragma unroll
      for (int kk = 0; kk < 4; ++kk) w[t][kk] = load_w_frag(Wap, kk * 32, t * 16, lane);
      ba[t] = bap[t * 16 + r];
    }

    int row0 = tile * 16;
    int ar = row0 + r, kb = (lane >> 4) * 8;
    short8 a0 = load_a_frag(h, ar, kb);
    short8 a1 = load_a_frag(h, ar, 32 + kb);
    short8 a2 = load_a_frag(hc, ar, kb);
    short8 a3 = load_a_frag(hc, ar, 32 + kb);

    f32x4 zero = {0.f, 0.f, 0.f, 0.f};
    f32x4 acc[4];
#pragma unroll
    for (int t = 0; t < 4; ++t) {
      acc[t] = mfma16(a0, w[t][0], zero);
      acc[t] = mfma16(a1, w[t][1], acc[t]);
      acc[t] = mfma16(a2, w[t][2], acc[t]);
      acc[t] = mfma16(a3, w[t][3], acc[t]);
    }

    float v[4][4];
#pragma unroll
    for (int t = 0; t < 4; ++t)
#pragma unroll
      for (int q = 0; q < 4; ++q) v[t][q] = acc[t][q] + ba[t];

#pragma unroll
    for (int q = 0; q < 4; ++q) {
      float sq = v[0][q] * v[0][q] + v[1][q] * v[1][q] + v[2][q] * v[2][q] +
                 v[3][q] * v[3][q];
      sq += __shfl_xor(sq, 1);
      sq += __shfl_xor(sq, 2);
      sq += __shfl_xor(sq, 4);
      sq += __shfl_xor(sq, 8);
      float sc = __fdividef(1.0f, fmaxf(sqrtf(sq), EPS_NORM));
      int row = row0 + (lane >> 4) * 4 + q;
#pragma unroll
      for (int t = 0; t < 4; ++t) {
        float hn = v[t][q] * sc;
        hn = (hn > 0.0f) ? hn : 0.0f;
        hc[row * 64 + t * 16 + r] = hn;
        hs[t] += hn;
        hq[t] += hn * hn;
      }
    }
  }

  if (threadIdx.x < 64) { ssum[threadIdx.x] = 0.f; ssq[threadIdx.x] = 0.f; }
  __syncthreads();
#pragma unroll
  for (int t = 0; t < 4; ++t) {
    int col = t * 16 + r;
    atomicAdd(&ssum[col], hs[t]);
    atomicAdd(&ssq[col], hq[t]);
  }
  __syncthreads();
  if (threadIdx.x < 64) {
    atomicAdd(&gsum[threadIdx.x], ssum[threadIdx.x]);
    atomicAdd(&gsq[threadIdx.x], ssq[threadIdx.x]);
  }
}

// ---------------- K4: fold stats into scale/offset per column ---------------
__global__ void k_stats(const float* __restrict__ sum_e, const float* __restrict__ sq_e,
                        const float* __restrict__ sum_h, const float* __restrict__ sq_h,
                        const float* __restrict__ gamma_e, const float* __restrict__ beta_e,
                        const float* __restrict__ gamma_h, const float* __restrict__ beta_h,
                        float* __restrict__ se, float* __restrict__ oe,
                        float* __restrict__ sh, float* __restrict__ oh) {
  int j = threadIdx.x;
  if (j < 64) {
    float mu = sum_e[j] / (float)NE;
    float var = fmaxf(sq_e[j] / (float)NE - mu * mu, 0.0f);
    float s = gamma_e[j] / sqrtf(var + EPS_BN);
    se[j] = s;
    oe[j] = beta_e[j] - mu * s;
    mu = sum_h[j] / (float)NN;
    var = fmaxf(sq_h[j] / (float)NN - mu * mu, 0.0f);
    s = gamma_h[j] / sqrtf(var + EPS_BN);
    sh[j] = s;
    oh[j] = beta_h[j] - mu * s;
  }
}

// ---------------- K5: h_out = h + BN(h_new)  (in place over stage) ----------
__global__ void __launch_bounds__(256) k_fin_h(const float* __restrict__ h,
                                               const float* __restrict__ sh,
                                               const float* __restrict__ oh,
                                               float* __restrict__ outh) {
  int i = (blockIdx.x * 256 + threadIdx.x) * 4;
  if (i >= NN * 64) return;
  f32x4 x = *reinterpret_cast<const f32x4*>(outh + i);
  f32x4 hv = *reinterpret_cast<const f32x4*>(h + i);
  int c0 = i & 63;
  f32x4 rr;
#pragma unroll
  for (int j = 0; j < 4; ++j) rr[j] = hv[j] + x[j] * sh[c0 + j] + oh[c0 + j];
  *reinterpret_cast<f32x4*>(outh + i) = rr;
}

// ---------------- K6: e_out = e + BN(relu(e_ij)) — pure streaming -----------
__global__ void __launch_bounds__(256) k_fin_e_stream(
    const float* __restrict__ e, const unsigned short* __restrict__ stage,
    const float* __restrict__ se, const float* __restrict__ oe,
    float* __restrict__ oute) {
  __shared__ float s_se[64], s_oe[64];
  if (threadIdx.x < 64) {
    s_se[threadIdx.x] = se[threadIdx.x];
    s_oe[threadIdx.x] = oe[threadIdx.x];
  }
  __syncthreads();
  size_t i8 = (size_t)blockIdx.x * 256 + threadIdx.x;  // grid sized exactly
  size_t i = i8 * 8;
  ushort8 sv = *reinterpret_cast<const ushort8*>(stage + i);
  f32x4 e0 = *reinterpret_cast<const f32x4*>(e + i);
  f32x4 e1 = *reinterpret_cast<const f32x4*>(e + i + 4);
  int c0 = (int)(i & 63);
  f32x4 r0, r1;
#pragma unroll
  for (int j = 0; j < 4; ++j) {
    float x = b2f(sv[j]);
    float rx = (x > 0.0f) ? x : 0.0f;
    r0[j] = e0[j] + rx * s_se[c0 + j] + s_oe[c0 + j];
  }
#pragma unroll
  for (int j = 0; j < 4; ++j) {
    float x = b2f(sv[4 + j]);
    float rx = (x > 0.0f) ? x : 0.0f;
    r1[j] = e1[j] + rx * s_se[c0 + 4 + j] + s_oe[c0 + 4 + j];
  }
  *reinterpret_cast<f32x4*>(oute + i) = r0;
  *reinterpret_cast<f32x4*>(oute + i + 4) = r1;
}

// ---------------------------------------------------------------------------
extern "C" void kernel_launch(void* const* d_in, const int* in_sizes, int n_in,
                              void* d_out, int out_size, void* d_ws, size_t ws_size,
                              hipStream_t stream) {
  (void)in_sizes; (void)n_in; (void)out_size; (void)ws_size;
  const float* h   = (const float*)d_in[0];
  const float* e   = (const float*)d_in[1];
  const int*   src = (const int*)d_in[2];
  const int*   dst = (const int*)d_in[3];
  const float* AW  = (const float*)d_in[4];
  const float* Ab  = (const float*)d_in[5];
  const float* BW  = (const float*)d_in[6];
  const float* Bb  = (const float*)d_in[7];
  const float* CW  = (const float*)d_in[8];
  const float* Cb  = (const float*)d_in[9];
  const float* Wap = (const float*)d_in[10];
  const float* bap = (const float*)d_in[11];
  const float* gamma_h = (const float*)d_in[12];
  const float* beta_h  = (const float*)d_in[13];
  const float* gamma_e = (const float*)d_in[14];
  const float* beta_e  = (const float*)d_in[15];

  float* ws = (float*)d_ws;
  float* Ah_p  = ws;                      // 3.2M floats, permuted layout
  float* Bh_p  = ws + 3200000;            // 3.2M floats, permuted layout
  float* stats = ws + 6400000;            // 512 floats
  float* sum_e = stats;
  float* sq_e  = stats + 64;
  float* sum_h = stats + 128;
  float* sq_h  = stats + 192;
  float* se    = stats + 256;
  float* oe    = stats + 320;
  float* sh    = stats + 384;
  float* oh    = stats + 448;

  int* deg    = (int*)(ws + 6400512);  // 50000
  int* off    = deg + NN;              // 50000
  int* bsum   = off + NN;              // 256
  int* bbase  = bsum + 256;            // 256
  int* cursor = bbase + 256;           // 50000
  int* perm   = cursor + NN;           // 800000
  unsigned short* stage = (unsigned short*)(ws + 7351024);  // NE*64 u16

  float* outh = (float*)d_out;
  float* oute = outh + (size_t)NN * 64;
  float* cbuf = outh;  // c lives in the h-output region until k_apply

  k_init<<<3125, 256, 0, stream>>>((u32x4*)cbuf, deg, stats);
  k_deg<<<(NE + 255) / 256, 256, 0, stream>>>(dst, deg);
  k_scan_local<<<NB_SCAN, 256, 0, stream>>>(deg, off, bsum);
  k_scan_base<<<1, 256, 0, stream>>>(bsum, bbase);
  k_scan_fix<<<NB_SCAN, 256, 0, stream>>>(bbase, off, cursor);
  k_scatter<<<(NE + 255) / 256, 256, 0, stream>>>(dst, cursor, perm);

  k_node_lin<<<(NT_N + 3) / 4, 256, 0, stream>>>(h, AW, Ab, BW, Bb, Ah_p, Bh_p);
  k_edge_sorted<<<2048, 256, 0, stream>>>(e, src, dst, perm, CW, Cb, Ah_p,
                                          Bh_p, cbuf, stage, sum_e, sq_e);
  k_apply<<<(NT_N + 3) / 4, 256, 0, stream>>>(h, cbuf, Wap, bap, sum_h, sq_h);
  k_stats<<<1, 64, 0, stream>>>(sum_e, sq_e, sum_h, sq_h, gamma_e, beta_e,
                                gamma_h, beta_h, se, oe, sh, oh);
  k_fin_h<<<NN * 64 / 1024, 256, 0, stream>>>(h, sh, oh, outh);
  k_fin_e_stream<<<NE * 64 / (256 * 8), 256, 0, stream>>>(e, stage, se, oe, oute);
}